// Round 1
// baseline (1041.592 us; speedup 1.0000x reference)
//
#include <hip/hip_runtime.h>
#include <math.h>

#define NTOT   131072        // B * NPG
#define NPG    2048
#define NB     64
#define KNNK   10
#define HID    64
#define EPSPN  1e-5f

// ---------------------------------------------------------------------------
// kNN: one block of 256 threads handles 256 queries of one graph; the graph's
// 2048 float2 positions live in LDS (16 KB). Each thread keeps a sorted
// top-10 (d2, idx) in registers; stable insertion == lax.top_k tie-break.
// ---------------------------------------------------------------------------
__global__ __launch_bounds__(256) void knn_kernel(const float2* __restrict__ pos,
                                                  int* __restrict__ knn)
{
    __shared__ float2 sp[NPG];
    const int g    = blockIdx.x >> 3;        // 8 blocks per graph
    const int base = g * NPG;
    for (int t = threadIdx.x; t < NPG; t += 256) sp[t] = pos[base + t];
    __syncthreads();

    const int ql = ((blockIdx.x & 7) << 8) + threadIdx.x;   // local query id
    const float qx = sp[ql].x, qy = sp[ql].y;

    float bd[KNNK];
    int   bi[KNNK];
#pragma unroll
    for (int k = 0; k < KNNK; ++k) { bd[k] = INFINITY; bi[k] = 0; }

    for (int j = 0; j < NPG; ++j) {
        // match reference arithmetic exactly: sub, mul, add (no FMA contraction)
        float dx = __fsub_rn(qx, sp[j].x);
        float dy = __fsub_rn(qy, sp[j].y);
        float d2 = __fadd_rn(__fmul_rn(dx, dx), __fmul_rn(dy, dy));
        if (j == ql) continue;               // loop=False (diag = inf)
        if (d2 < bd[KNNK - 1]) {             // strict: later index loses ties
#pragma unroll
            for (int k = KNNK - 1; k >= 0; --k) {
                float dp = (k > 0) ? bd[k - 1] : -INFINITY;
                int   ip = (k > 0) ? bi[k - 1] : 0;
                bool shift = (dp > d2);                  // strictly greater shifts
                bool place = (!shift) && (bd[k] > d2);   // stable placement
                if (shift)      { bd[k] = dp; bi[k] = ip; }
                else if (place) { bd[k] = d2; bi[k] = j; }
            }
        }
    }

    const int q = base + ql;
#pragma unroll
    for (int k = 0; k < KNNK; ++k) knn[q * KNNK + k] = base + bi[k];
}

// ---------------------------------------------------------------------------
// conv1: msg = rel @ W1 + b1 ; h = relu(max over edges incl. self (rel=0))
// one wave per node, lane = output channel.
// ---------------------------------------------------------------------------
__global__ __launch_bounds__(256) void conv1_kernel(const float2* __restrict__ pos,
        const int* __restrict__ knn, const float* __restrict__ W1,
        const float* __restrict__ b1, float* __restrict__ out)
{
    const int lane = threadIdx.x & 63;
    const int nw   = (gridDim.x * blockDim.x) >> 6;
    const float w0 = W1[lane], w1 = W1[HID + lane], bb = b1[lane];
    for (int i = (blockIdx.x * blockDim.x + threadIdx.x) >> 6; i < NTOT; i += nw) {
        float2 pi = pos[i];
        float acc = bb;                       // self edge: rel = 0 -> msg = b1
#pragma unroll
        for (int e = 0; e < KNNK; ++e) {
            int j = knn[i * KNNK + e];
            float2 pj = pos[j];
            float rx = pj.x - pi.x, ry = pj.y - pi.y;
            float m = rx * w0 + ry * w1 + bb;
            acc = fmaxf(acc, m);
        }
        out[i * HID + lane] = fmaxf(acc, 0.f);   // relu AFTER segment_max
    }
}

// ---------------------------------------------------------------------------
// reduce: colsum[64] and raw sum of squares over [NTOT, 64] buffer
// (st[0..63] = colsum, st[64] = sumsq) -- st must be pre-zeroed.
// ---------------------------------------------------------------------------
__global__ __launch_bounds__(256) void reduce_kernel(const float* __restrict__ buf,
                                                     float* __restrict__ st)
{
    const int tid = threadIdx.x;
    float cs = 0.f, ss = 0.f;
    const int total = NTOT * HID;
    const int stride = gridDim.x * 256;       // multiple of 64 -> fixed column
    for (int idx = blockIdx.x * 256 + tid; idx < total; idx += stride) {
        float v = buf[idx];
        cs += v; ss += v * v;
    }
    __shared__ float scs[256];
    scs[tid] = cs; __syncthreads();
    if (tid < 64) {
        float c4 = scs[tid] + scs[tid + 64] + scs[tid + 128] + scs[tid + 192];
        atomicAdd(&st[tid], c4);
    }
#pragma unroll
    for (int o = 32; o > 0; o >>= 1) ss += __shfl_xor(ss, o, 64);
    __syncthreads();
    if ((tid & 63) == 0) scs[tid >> 6] = ss;
    __syncthreads();
    if (tid == 0) atomicAdd(&st[64], scs[0] + scs[1] + scs[2] + scs[3]);
}

// ---------------------------------------------------------------------------
// stats: mean[c]=colsum/N -> st[128+c]; inv = 1/sqrt(eps + s) -> st[66];
// offs[c] = b_next[c] - inv * sum_k mean_k * Wnext[k][c] -> st[192+c]
// ---------------------------------------------------------------------------
__global__ __launch_bounds__(64) void stats_kernel(float* __restrict__ st,
        const float* __restrict__ Wn, const float* __restrict__ bn)
{
    const int c = threadIdx.x;                 // 64 threads = 1 wave
    float mean = st[c] * (1.0f / (float)NTOT);
    st[128 + c] = mean;
    float m2 = mean * mean;
#pragma unroll
    for (int o = 32; o > 0; o >>= 1) m2 += __shfl_xor(m2, o, 64);
    float s = (st[64] - (float)NTOT * m2) * (1.0f / (float)NTOT);
    s = fmaxf(s, 0.f);
    float inv = 1.0f / sqrtf(EPSPN + s);
    if (c == 0) st[66] = inv;
    if (Wn != nullptr) {
        float dot = 0.f;
#pragma unroll
        for (int k = 0; k < HID; ++k) dot += __shfl(mean, k, 64) * Wn[k * HID + c];
        st[192 + c] = bn[c] - inv * dot;
    }
}

// ---------------------------------------------------------------------------
// gemmA: xw[i][c] = inv * (h_raw[i] @ Wa)[c] + offs[c]
//      == ((h_raw[i]-mean)*inv) @ Wa + b    (normalization folded in)
// one wave per node; lane k holds x_k, broadcast via shuffle; Wa staged in LDS.
// ---------------------------------------------------------------------------
__global__ __launch_bounds__(256) void gemmA_kernel(const float* __restrict__ hin,
        const float* __restrict__ Wa, const float* __restrict__ st,
        float* __restrict__ xw)
{
    __shared__ float sw[HID * HID];
    for (int t = threadIdx.x; t < HID * HID; t += 256) sw[t] = Wa[t];
    const int lane = threadIdx.x & 63;
    const float inv  = st[66];
    const float offs = st[192 + lane];
    __syncthreads();
    const int nw = (gridDim.x * blockDim.x) >> 6;
    for (int i = (blockIdx.x * blockDim.x + threadIdx.x) >> 6; i < NTOT; i += nw) {
        float x = hin[i * HID + lane];
        float acc = 0.f;
#pragma unroll
        for (int k = 0; k < HID; ++k)
            acc += __shfl(x, k, 64) * sw[k * HID + lane];
        xw[i * HID + lane] = inv * acc + offs;
    }
}

// ---------------------------------------------------------------------------
// convB: h_out = relu( max_{j in nbr(i) U {i}} ( xw[j] + rel_ij @ Wb ) )
// Wb = rows 64..65 of the [66,64] weight. Self edge: rel=0 -> xw[i].
// ---------------------------------------------------------------------------
__global__ __launch_bounds__(256) void convB_kernel(const float2* __restrict__ pos,
        const int* __restrict__ knn, const float* __restrict__ xw,
        const float* __restrict__ Wb, float* __restrict__ out)
{
    const int lane = threadIdx.x & 63;
    const float wb0 = Wb[lane], wb1 = Wb[HID + lane];
    const int nw = (gridDim.x * blockDim.x) >> 6;
    for (int i = (blockIdx.x * blockDim.x + threadIdx.x) >> 6; i < NTOT; i += nw) {
        float2 pi = pos[i];
        float acc = xw[i * HID + lane];        // self edge
#pragma unroll
        for (int e = 0; e < KNNK; ++e) {
            int j = knn[i * KNNK + e];
            float2 pj = pos[j];
            float rx = pj.x - pi.x, ry = pj.y - pi.y;
            float m = xw[j * HID + lane] + rx * wb0 + ry * wb1;
            acc = fmaxf(acc, m);
        }
        out[i * HID + lane] = fmaxf(acc, 0.f);
    }
}

// ---------------------------------------------------------------------------
// pool + MLP head: per-graph column max of raw h3 (max is monotone under the
// positive affine PairNorm), then normalize once, then 64->64 relu -> 64->2.
// ---------------------------------------------------------------------------
__global__ __launch_bounds__(1024) void pool_kernel(const float* __restrict__ h,
        const float* __restrict__ st, const float* __restrict__ Wl1,
        const float* __restrict__ bl1, const float* __restrict__ Wl2,
        const float* __restrict__ bl2, float* __restrict__ out)
{
    const int b  = blockIdx.x;
    const int c  = threadIdx.x & 63;
    const int rg = threadIdx.x >> 6;           // 0..15
    float m = -INFINITY;
    for (int r = rg; r < NPG; r += 16)
        m = fmaxf(m, h[(b * NPG + r) * HID + c]);
    __shared__ float sm[16][HID];
    __shared__ float sg[HID], sh1[HID];
    sm[rg][c] = m; __syncthreads();
    if (threadIdx.x < 64) {
        float mm = sm[0][c];
#pragma unroll
        for (int g2 = 1; g2 < 16; ++g2) mm = fmaxf(mm, sm[g2][c]);
        sg[c] = (mm - st[128 + c]) * st[66];   // pair_norm of the max
    }
    __syncthreads();
    if (threadIdx.x < 64) {
        float a = bl1[c];
#pragma unroll
        for (int k = 0; k < HID; ++k) a += sg[k] * Wl1[k * HID + c];
        sh1[c] = fmaxf(a, 0.f);                // relu (dropout = identity)
    }
    __syncthreads();
    if (threadIdx.x < 2) {
        float a = bl2[threadIdx.x];
#pragma unroll
        for (int k = 0; k < HID; ++k) a += sh1[k] * Wl2[k * 2 + threadIdx.x];
        out[b * 2 + threadIdx.x] = a;
    }
}

// ---------------------------------------------------------------------------
extern "C" void kernel_launch(void* const* d_in, const int* in_sizes, int n_in,
                              void* d_out, int out_size, void* d_ws, size_t ws_size,
                              hipStream_t stream)
{
    const float2* pos = (const float2*)d_in[0];
    // d_in[1] = batch (unused: equal-sized contiguous graphs)
    const float* W1  = (const float*)d_in[2];
    const float* b1  = (const float*)d_in[3];
    const float* W2  = (const float*)d_in[4];   // [66,64]
    const float* b2  = (const float*)d_in[5];
    const float* W3  = (const float*)d_in[6];   // [66,64]
    const float* b3  = (const float*)d_in[7];
    const float* Wl1 = (const float*)d_in[8];
    const float* bl1 = (const float*)d_in[9];
    const float* Wl2 = (const float*)d_in[10];
    const float* bl2 = (const float*)d_in[11];
    float* out = (float*)d_out;

    // workspace layout
    int*   knn  = (int*)d_ws;                                        // 5.24 MB
    float* bufA = (float*)((char*)d_ws + (size_t)NTOT * KNNK * 4);   // 33.5 MB
    float* bufB = bufA + (size_t)NTOT * HID;                         // 33.5 MB
    float* st   = bufB + (size_t)NTOT * HID;                         // 3 KB

    hipMemsetAsync(st, 0, 3 * 256 * sizeof(float), stream);

    knn_kernel  <<<NTOT / 256, 256, 0, stream>>>(pos, knn);

    // layer 1
    conv1_kernel<<<2048, 256, 0, stream>>>(pos, knn, W1, b1, bufA);
    reduce_kernel<<<1024, 256, 0, stream>>>(bufA, st);
    stats_kernel<<<1, 64, 0, stream>>>(st, W2, b2);

    // layer 2
    gemmA_kernel<<<2048, 256, 0, stream>>>(bufA, W2, st, bufB);
    convB_kernel<<<2048, 256, 0, stream>>>(pos, knn, bufB, W2 + 64 * HID, bufA);
    reduce_kernel<<<1024, 256, 0, stream>>>(bufA, st + 256);
    stats_kernel<<<1, 64, 0, stream>>>(st + 256, W3, b3);

    // layer 3
    gemmA_kernel<<<2048, 256, 0, stream>>>(bufA, W3, st + 256, bufB);
    convB_kernel<<<2048, 256, 0, stream>>>(pos, knn, bufB, W3 + 64 * HID, bufA);
    reduce_kernel<<<1024, 256, 0, stream>>>(bufA, st + 512);
    stats_kernel<<<1, 64, 0, stream>>>(st + 512, nullptr, nullptr);

    // pool + head
    pool_kernel<<<NB, 1024, 0, stream>>>(bufA, st + 512, Wl1, bl1, Wl2, bl2, out);
}

// Round 2
// 573.841 us; speedup vs baseline: 1.8151x; 1.8151x over previous
//
#include <hip/hip_runtime.h>
#include <math.h>

#define NTOT   131072        // B * NPG
#define NPG    2048
#define NB     64
#define KNNK   10
#define HID    64
#define EPSPN  1e-5f

__device__ inline float rdlane(float v, int l) {
    return __int_as_float(__builtin_amdgcn_readlane(__float_as_int(v), l));
}

// ---------------------------------------------------------------------------
// sort: per graph, bitonic sort of 2048 points by x (sortable-uint key),
// then write the permuted positions to spos. Order within ties arbitrary
// (scan order only; selection is exact).
// ---------------------------------------------------------------------------
__global__ __launch_bounds__(1024) void sort_kernel(const float2* __restrict__ pos,
                                                    float2* __restrict__ spos)
{
    __shared__ unsigned sk[NPG];
    __shared__ unsigned sv[NPG];
    const int base = blockIdx.x * NPG;
    const int tid  = threadIdx.x;
    for (int t = tid; t < NPG; t += 1024) {
        unsigned u = __float_as_uint(pos[base + t].x);
        sk[t] = (u & 0x80000000u) ? ~u : (u | 0x80000000u);
        sv[t] = (unsigned)t;
    }
    __syncthreads();
    for (int k = 2; k <= NPG; k <<= 1) {
        for (int j = k >> 1; j > 0; j >>= 1) {
            int i = ((tid & ~(j - 1)) << 1) | (tid & (j - 1));
            int l = i + j;
            bool up = ((i & k) == 0);
            unsigned a = sk[i], b = sk[l];
            if ((a > b) == up) {
                sk[i] = b; sk[l] = a;
                unsigned t2 = sv[i]; sv[i] = sv[l]; sv[l] = t2;
            }
            __syncthreads();
        }
    }
    for (int t = tid; t < NPG; t += 1024)
        spos[base + t] = pos[base + sv[t]];
}

// ---------------------------------------------------------------------------
// knn over sorted points: outward two-pointer scan from own sorted position.
// Unsorted top-10 with invariant "slot 9 holds the max"; insertion replaces
// slot 9 then restores the invariant with a 9-step compare&swap ladder.
// Indices stored as u16 local (within-graph, sorted space).
// ---------------------------------------------------------------------------
#define INSERT(INS, D2, JJ) do {                                              \
    bd[9] = (INS) ? (D2) : bd[9];                                             \
    bi[9] = (INS) ? (JJ) : bi[9];                                             \
    _Pragma("unroll")                                                         \
    for (int kk = 0; kk < 9; ++kk) {                                          \
        bool sw_ = bd[kk] > bd[9];                                            \
        float tv_ = bd[kk]; int ti_ = bi[kk];                                 \
        bd[kk] = sw_ ? bd[9] : bd[kk]; bi[kk] = sw_ ? bi[9] : bi[kk];         \
        bd[9]  = sw_ ? tv_  : bd[9];   bi[9]  = sw_ ? ti_  : bi[9];           \
    }                                                                         \
} while (0)

__global__ __launch_bounds__(256) void knn_kernel(const float2* __restrict__ spos,
                                                  unsigned short* __restrict__ knn)
{
    __shared__ float2 sp[NPG];
    const int g    = blockIdx.x >> 3;
    const int base = g * NPG;
    for (int t = threadIdx.x; t < NPG; t += 256) sp[t] = spos[base + t];
    __syncthreads();

    const int pl = ((blockIdx.x & 7) << 8) + threadIdx.x;   // local sorted pos
    const float qx = sp[pl].x, qy = sp[pl].y;

    float bd[KNNK];
    int   bi[KNNK];
#pragma unroll
    for (int k = 0; k < KNNK; ++k) { bd[k] = INFINITY; bi[k] = 0; }

    const int nl = pl, nr = (NPG - 1) - pl;
    const int m  = (nl < nr) ? nl : nr;

#pragma unroll 2
    for (int s = 1; s <= m; ++s) {
        const int jl = pl - s, jr = pl + s;
        float2 pjl = sp[jl], pjr = sp[jr];
        float dxl = __fsub_rn(qx, pjl.x), dyl = __fsub_rn(qy, pjl.y);
        float d2l = __fadd_rn(__fmul_rn(dxl, dxl), __fmul_rn(dyl, dyl));
        float dxr = __fsub_rn(qx, pjr.x), dyr = __fsub_rn(qy, pjr.y);
        float d2r = __fadd_rn(__fmul_rn(dxr, dxr), __fmul_rn(dyr, dyr));
        bool insl = d2l < bd[9];
        bool pre  = insl || (d2r < bd[9]);     // conservative (thr only shrinks)
        if (__any(pre)) {
            INSERT(insl, d2l, jl);
            bool insr = d2r < bd[9];
            INSERT(insr, d2r, jr);
        }
    }
    for (int s = m + 1; s <= nl; ++s) {
        const int j = pl - s;
        float2 pj = sp[j];
        float dx = __fsub_rn(qx, pj.x), dy = __fsub_rn(qy, pj.y);
        float d2 = __fadd_rn(__fmul_rn(dx, dx), __fmul_rn(dy, dy));
        bool ins = d2 < bd[9];
        if (__any(ins)) INSERT(ins, d2, j);
    }
    for (int s = m + 1; s <= nr; ++s) {
        const int j = pl + s;
        float2 pj = sp[j];
        float dx = __fsub_rn(qx, pj.x), dy = __fsub_rn(qy, pj.y);
        float d2 = __fadd_rn(__fmul_rn(dx, dx), __fmul_rn(dy, dy));
        bool ins = d2 < bd[9];
        if (__any(ins)) INSERT(ins, d2, j);
    }

    const int row = (base + pl) * KNNK;
#pragma unroll
    for (int k = 0; k < KNNK; ++k) knn[row + k] = (unsigned short)bi[k];
}

// ---------------------------------------------------------------------------
// conv1 (+fused PairNorm reduction): block = 128 consecutive sorted nodes.
// ---------------------------------------------------------------------------
__global__ __launch_bounds__(256) void conv1_kernel(const float2* __restrict__ spos,
        const unsigned short* __restrict__ knn, const float* __restrict__ W1,
        const float* __restrict__ b1, float* __restrict__ out, float* __restrict__ st)
{
    __shared__ float red[256];
    const int tid  = threadIdx.x;
    const int lane = tid & 63, w = tid >> 6;
    const int i0   = blockIdx.x * 128 + w * 32;
    const int base = (blockIdx.x >> 4) << 11;       // graph start (2048-aligned)
    const float w0 = W1[lane], w1 = W1[HID + lane], bb = b1[lane];
    float cs = 0.f, ss = 0.f;
    for (int r = 0; r < 32; ++r) {
        const int i = i0 + r;
        float2 pi = spos[i];
        float acc = bb;                              // self edge (rel = 0)
#pragma unroll
        for (int e = 0; e < KNNK; ++e) {
            int j = base + (int)knn[i * KNNK + e];
            float2 pj = spos[j];
            float rx = pj.x - pi.x, ry = pj.y - pi.y;
            acc = fmaxf(acc, fmaf(rx, w0, fmaf(ry, w1, bb)));
        }
        float v = fmaxf(acc, 0.f);
        out[i * HID + lane] = v;
        cs += v; ss = fmaf(v, v, ss);
    }
    red[tid] = cs; __syncthreads();
    if (tid < 64) atomicAdd(&st[tid], red[tid] + red[tid + 64] + red[tid + 128] + red[tid + 192]);
#pragma unroll
    for (int o = 32; o > 0; o >>= 1) ss += __shfl_xor(ss, o, 64);
    __syncthreads();
    if (lane == 0) red[w] = ss;
    __syncthreads();
    if (tid == 0) atomicAdd(&st[64], red[0] + red[1] + red[2] + red[3]);
}

// ---------------------------------------------------------------------------
// stats: mean, inv = 1/sqrt(eps + var-of-rows), offs = b_next - inv*mean@Wnext
// ---------------------------------------------------------------------------
__global__ __launch_bounds__(64) void stats_kernel(float* __restrict__ st,
        const float* __restrict__ Wn, const float* __restrict__ bn)
{
    const int c = threadIdx.x;
    float mean = st[c] * (1.0f / (float)NTOT);
    st[128 + c] = mean;
    float m2 = mean * mean;
#pragma unroll
    for (int o = 32; o > 0; o >>= 1) m2 += __shfl_xor(m2, o, 64);
    float s = (st[64] - (float)NTOT * m2) * (1.0f / (float)NTOT);
    s = fmaxf(s, 0.f);
    float inv = 1.0f / sqrtf(EPSPN + s);
    if (c == 0) st[66] = inv;
    if (Wn != nullptr) {
        float dot = 0.f;
#pragma unroll
        for (int k = 0; k < HID; ++k) dot = fmaf(rdlane(mean, k), Wn[k * HID + c], dot);
        st[192 + c] = bn[c] - inv * dot;
    }
}

// ---------------------------------------------------------------------------
// gemmA (in-place): buf[i] <- inv*(buf[i] @ Wa) + offs. W column in registers,
// x broadcast via v_readlane.
// ---------------------------------------------------------------------------
__global__ __launch_bounds__(256) void gemmA_kernel(float* __restrict__ buf,
        const float* __restrict__ Wa, const float* __restrict__ st)
{
    const int tid  = threadIdx.x;
    const int lane = tid & 63, w = tid >> 6;
    float wcol[HID];
#pragma unroll
    for (int k = 0; k < HID; ++k) wcol[k] = Wa[k * HID + lane];
    const float inv  = st[66];
    const float offs = st[192 + lane];
    const int i0 = blockIdx.x * 128 + w * 32;
    for (int r = 0; r < 32; ++r) {
        const int i = i0 + r;
        float x = buf[i * HID + lane];
        float acc = 0.f;
#pragma unroll
        for (int k = 0; k < HID; ++k) acc = fmaf(rdlane(x, k), wcol[k], acc);
        buf[i * HID + lane] = fmaf(inv, acc, offs);
    }
}

// ---------------------------------------------------------------------------
// convB (+fused reduction; DO_MAX also fuses the per-graph column max and
// skips the global write — used for layer 3).
// ---------------------------------------------------------------------------
template <int DO_MAX>
__global__ __launch_bounds__(256) void convB_kernel(const float2* __restrict__ spos,
        const unsigned short* __restrict__ knn, const float* __restrict__ xw,
        const float* __restrict__ Wb, float* __restrict__ out,
        float* __restrict__ st, float* __restrict__ gmax)
{
    __shared__ float red[256];
    const int tid  = threadIdx.x;
    const int lane = tid & 63, w = tid >> 6;
    const int i0   = blockIdx.x * 128 + w * 32;
    const int base = (blockIdx.x >> 4) << 11;
    const float wb0 = Wb[lane], wb1 = Wb[HID + lane];
    float cs = 0.f, ss = 0.f, gm = 0.f;
    for (int r = 0; r < 32; ++r) {
        const int i = i0 + r;
        float2 pi = spos[i];
        float acc = xw[i * HID + lane];              // self edge
#pragma unroll
        for (int e = 0; e < KNNK; ++e) {
            int j = base + (int)knn[i * KNNK + e];
            float2 pj = spos[j];
            float rx = pj.x - pi.x, ry = pj.y - pi.y;
            acc = fmaxf(acc, fmaf(rx, wb0, fmaf(ry, wb1, xw[j * HID + lane])));
        }
        float v = fmaxf(acc, 0.f);
        if (!DO_MAX) out[i * HID + lane] = v;
        cs += v; ss = fmaf(v, v, ss);
        if (DO_MAX) gm = fmaxf(gm, v);
    }
    red[tid] = cs; __syncthreads();
    if (tid < 64) atomicAdd(&st[tid], red[tid] + red[tid + 64] + red[tid + 128] + red[tid + 192]);
#pragma unroll
    for (int o = 32; o > 0; o >>= 1) ss += __shfl_xor(ss, o, 64);
    __syncthreads();
    if (lane == 0) red[w] = ss;
    __syncthreads();
    if (tid == 0) atomicAdd(&st[64], red[0] + red[1] + red[2] + red[3]);
    if (DO_MAX) {
        const int g = blockIdx.x >> 4;
        atomicMax((int*)gmax + g * HID + lane, __float_as_int(gm));  // v >= 0
    }
}

// ---------------------------------------------------------------------------
// head: normalize per-graph max (monotone under positive affine PairNorm),
// then 64->64 relu -> 64->2.
// ---------------------------------------------------------------------------
__global__ __launch_bounds__(64) void head_kernel(const float* __restrict__ gmax,
        const float* __restrict__ st3, const float* __restrict__ Wl1,
        const float* __restrict__ bl1, const float* __restrict__ Wl2,
        const float* __restrict__ bl2, float* __restrict__ out)
{
    const int b = blockIdx.x, c = threadIdx.x;
    float gv = (gmax[b * HID + c] - st3[128 + c]) * st3[66];
    float a = bl1[c];
#pragma unroll
    for (int k = 0; k < HID; ++k) a = fmaf(rdlane(gv, k), Wl1[k * HID + c], a);
    float h1 = fmaxf(a, 0.f);
    float o = bl2[c & 1];
#pragma unroll
    for (int k = 0; k < HID; ++k) o = fmaf(rdlane(h1, k), Wl2[k * 2 + (c & 1)], o);
    if (c < 2) out[b * 2 + c] = o;
}

// ---------------------------------------------------------------------------
extern "C" void kernel_launch(void* const* d_in, const int* in_sizes, int n_in,
                              void* d_out, int out_size, void* d_ws, size_t ws_size,
                              hipStream_t stream)
{
    const float2* pos = (const float2*)d_in[0];
    const float* W1  = (const float*)d_in[2];
    const float* b1  = (const float*)d_in[3];
    const float* W2  = (const float*)d_in[4];   // [66,64]
    const float* b2  = (const float*)d_in[5];
    const float* W3  = (const float*)d_in[6];   // [66,64]
    const float* b3  = (const float*)d_in[7];
    const float* Wl1 = (const float*)d_in[8];
    const float* bl1 = (const float*)d_in[9];
    const float* Wl2 = (const float*)d_in[10];
    const float* bl2 = (const float*)d_in[11];
    float* out = (float*)d_out;

    // workspace layout (~70.8 MB)
    char* p = (char*)d_ws;
    unsigned short* knn = (unsigned short*)p;            p += (size_t)NTOT * KNNK * 2;  // 2.62 MB
    float2* spos = (float2*)p;                           p += (size_t)NTOT * 8;         // 1.05 MB
    float* bufA  = (float*)p;                            p += (size_t)NTOT * HID * 4;   // 33.55 MB
    float* bufB  = (float*)p;                            p += (size_t)NTOT * HID * 4;   // 33.55 MB
    float* st    = (float*)p;                            // 3*256 floats
    float* gmax  = st + 768;                             // 64*64 floats

    hipMemsetAsync(st, 0, (768 + NB * HID) * sizeof(float), stream);

    sort_kernel<<<NB, 1024, 0, stream>>>(pos, spos);
    knn_kernel <<<NTOT / 256, 256, 0, stream>>>(spos, knn);

    // layer 1
    conv1_kernel<<<NTOT / 128, 256, 0, stream>>>(spos, knn, W1, b1, bufA, st);
    stats_kernel<<<1, 64, 0, stream>>>(st, W2, b2);

    // layer 2
    gemmA_kernel<<<NTOT / 128, 256, 0, stream>>>(bufA, W2, st);
    convB_kernel<0><<<NTOT / 128, 256, 0, stream>>>(spos, knn, bufA, W2 + 64 * HID,
                                                    bufB, st + 256, gmax);
    stats_kernel<<<1, 64, 0, stream>>>(st + 256, W3, b3);

    // layer 3
    gemmA_kernel<<<NTOT / 128, 256, 0, stream>>>(bufB, W3, st + 256);
    convB_kernel<1><<<NTOT / 128, 256, 0, stream>>>(spos, knn, bufB, W3 + 64 * HID,
                                                    bufA, st + 512, gmax);
    stats_kernel<<<1, 64, 0, stream>>>(st + 512, nullptr, nullptr);

    // head
    head_kernel<<<NB, 64, 0, stream>>>(gmax, st + 512, Wl1, bl1, Wl2, bl2, out);
}